// Round 20
// baseline (163.879 us; speedup 1.0000x reference)
//
#include <hip/hip_runtime.h>
#include <float.h>

#define DECAY 0.1f
#define OMD   0.9f
#define EPS   1e-5f
#define NORM_EPS 1e-8f

static constexpr int D = 32;

typedef __attribute__((ext_vector_type(8))) short s16x8;
typedef __attribute__((ext_vector_type(4))) float f32x4_t;

__device__ __forceinline__ float bf2f(short s) {
    return __uint_as_float(((unsigned int)(unsigned short)s) << 16);
}

struct Split3 { short b0, b1, b2; };

// Exact 3-way bf16 truncation split: v == b0 + b1 + b2 (fp32 mantissa = 24 bits = 3x8).
__device__ __forceinline__ Split3 split3(float v) {
    const unsigned int u0 = __float_as_uint(v) & 0xFFFF0000u;
    const float r  = v - __uint_as_float(u0);
    const unsigned int u1 = __float_as_uint(r) & 0xFFFF0000u;
    const float r2 = r - __uint_as_float(u1);
    Split3 s;
    s.b0 = (short)(u0 >> 16);
    s.b1 = (short)(u1 >> 16);
    s.b2 = (short)(__float_as_uint(r2) >> 16);
    return s;
}

// ---------------- K1: normalize codebook + pack MFMA B-tiles ----------------
// Per 16-code tile (3136 B global): 3 planes x 1024 B of bf16 B-fragments, then
// 16 floats of -|en|^2 (64 B). Lane l's fragment of plane p is the contiguous
// 16 B at tile_base + p*1024 + l*16 -> direct global_load_dwordx4 to VGPRs.
// B[k][col] = 2*en[tile*16+col][k]; lane l holds k-chunk l>>4, col l&15.
__global__ void prep_codebook(const float* __restrict__ embed,
                              unsigned short* __restrict__ bfrag,
                              int K) {
    const int k = blockIdx.x * blockDim.x + threadIdx.x;
    if (k >= K) return;
    float v[D]; float ssq = 0.f;
#pragma unroll
    for (int d = 0; d < D; ++d) { v[d] = embed[(size_t)k * D + d]; ssq += v[d] * v[d]; }
    const float inv = 1.0f / (sqrtf(ssq) + NORM_EPS);
    float e2 = 0.f;
    short p0[D], p1[D], p2[D];
#pragma unroll
    for (int d = 0; d < D; ++d) {
        const float e = v[d] * inv;
        e2 += e * e;
        const Split3 s = split3(2.0f * e);   // fold the *2 into the splits (exact)
        p0[d] = s.b0; p1[d] = s.b1; p2[d] = s.b2;
    }
    char* base = (char*)bfrag + (size_t)(k >> 4) * 3136;   // tile base, bytes
    const int col = k & 15;
    *(float*)(base + 3072 + col * 4) = -e2;
#pragma unroll
    for (int g = 0; g < 4; ++g) {                 // k-chunk g -> lane g*16+col
        const int lid = g * 16 + col;
        s16x8 s0, s1, s2;
#pragma unroll
        for (int i = 0; i < 8; ++i) { s0[i] = p0[g*8+i]; s1[i] = p1[g*8+i]; s2[i] = p2[g*8+i]; }
        *(s16x8*)(base +    0 + lid * 16) = s0;
        *(s16x8*)(base + 1024 + lid * 16) = s1;
        *(s16x8*)(base + 2048 + lid * 16) = s2;
    }
}

// B tile held entirely in registers (13 VGPRs).
struct Btile { s16x8 b0, b1, b2; float ne2; };

// ---- K2: MFMA assignment, 8 teams x 2-wave convoy, chain=32, inline scatter
// 1024 thr = 16 waves, 64 points/block, grid = N/64 = 1024 (2 blocks/CU -> 32
// waves/CU). Wave w: team = w>>1 (codes [team*K/8,(team+1)*K/8), chain = 32
// tiles -- the proven optimum), half = w&1 (points half*32..half*32+31). The
// 2 waves of a team stream the SAME tiles in convoy (L1 sharing; co-resident
// block scans the same code space too). Per-tile math and scatter are
// bit-identical to R15; only the wave->(team,points) map changed.
__global__ __launch_bounds__(1024)
void assign_kernel(const float* __restrict__ x,
                   const unsigned short* __restrict__ bfrag,
                   float* __restrict__ out_quant,
                   float* __restrict__ out_ind,
                   float* __restrict__ bins,
                   float* __restrict__ esum,
                   int N, int K) {
    constexpr int PB = 64;
    __shared__ char  sm[12288];          // 4 point-groups x 3072 B A-fragments
    __shared__ float teamS[8][PB];
    __shared__ float teamC[8][PB];
    __shared__ int   best_c[PB];

    const int tid  = threadIdx.x;
    const int lane = tid & 63;
    const int w    = tid >> 6;           // wave 0..15
    const int team = w >> 1;             // 0..7: codes [team*K/8,(team+1)*K/8)
    const int half = w & 1;              // which 32-point half of the block
    const int n0   = blockIdx.x * PB;
    const int col  = lane & 15;

    float fn_r[8];
    // ---- phase 1: load + normalize + exact split into A-fragment LDS ----
    // 4 threads per point, 8 floats each; threads 256..1023 idle here.
    if (tid < 4 * PB) {
        const int p = tid >> 2, q = tid & 3;
        const float* xp = &x[(size_t)(n0 + p) * D + q * 8];
        const float4 va = *(const float4*)(xp);
        const float4 vb = *(const float4*)(xp + 4);
        float ssq = va.x*va.x + va.y*va.y + va.z*va.z + va.w*va.w
                  + vb.x*vb.x + vb.y*vb.y + vb.z*vb.z + vb.w*vb.w;
        ssq += __shfl_xor(ssq, 1);
        ssq += __shfl_xor(ssq, 2);
        const float inv = 1.0f / (sqrtf(ssq) + NORM_EPS);
        fn_r[0]=va.x*inv; fn_r[1]=va.y*inv; fn_r[2]=va.z*inv; fn_r[3]=va.w*inv;
        fn_r[4]=vb.x*inv; fn_r[5]=vb.y*inv; fn_r[6]=vb.z*inv; fn_r[7]=vb.w*inv;
        // A-frag: group g=p>>4, k-chunk q -> lane q*16+(p&15), planes stride 1024B
        char* dst = &sm[(p >> 4) * 3072 + (q * 16 + (p & 15)) * 16];
        s16x8 s0, s1, s2;
#pragma unroll
        for (int i = 0; i < 8; ++i) {
            const Split3 s = split3(fn_r[i]);
            s0[i] = s.b0; s1[i] = s.b1; s2[i] = s.b2;
        }
        *(s16x8*)(dst) = s0; *(s16x8*)(dst + 1024) = s1; *(s16x8*)(dst + 2048) = s2;
    }
    __syncthreads();

    // ---- A fragments to registers: this wave's 2 point-groups x 3 planes ----
    s16x8 A[2][3];
#pragma unroll
    for (int pg = 0; pg < 2; ++pg) {
#pragma unroll
        for (int pl = 0; pl < 3; ++pl)
            A[pg][pl] = *(const s16x8*)&sm[(half * 2 + pg) * 3072 + pl * 1024 + lane * 16];
    }

    float bestS[2][4], bestC[2][4];
#pragma unroll
    for (int pg = 0; pg < 2; ++pg)
#pragma unroll
        for (int r = 0; r < 4; ++r) { bestS[pg][r] = -1e30f; bestC[pg][r] = 0.f; }

    const int NT = K >> 4;               // 256 tiles
    const int HT = NT >> 3;              // 32 tiles per team
    const int t0 = team * HT;            // this team's first tile
    const char* gp  = (const char*)bfrag + (size_t)t0 * 3136 + lane * 16;
    const char* gpe = (const char*)bfrag + (size_t)t0 * 3136 + 3072 + (size_t)col * 4;

    auto compute = [&](const Btile& T, float codef) {
        const f32x4_t initX = {T.ne2, T.ne2, T.ne2, T.ne2};   // -|en|^2 folded into C
#pragma unroll
        for (int pg = 0; pg < 2; ++pg) {
            // 6 split products in ONE accumulator chain (C-in carries sum).
            f32x4_t X = __builtin_amdgcn_mfma_f32_16x16x32_bf16(A[pg][0], T.b0, initX, 0, 0, 0);
            X = __builtin_amdgcn_mfma_f32_16x16x32_bf16(A[pg][0], T.b1, X, 0, 0, 0);
            X = __builtin_amdgcn_mfma_f32_16x16x32_bf16(A[pg][1], T.b1, X, 0, 0, 0);
            X = __builtin_amdgcn_mfma_f32_16x16x32_bf16(A[pg][1], T.b0, X, 0, 0, 0);
            X = __builtin_amdgcn_mfma_f32_16x16x32_bf16(A[pg][0], T.b2, X, 0, 0, 0);
            X = __builtin_amdgcn_mfma_f32_16x16x32_bf16(A[pg][2], T.b0, X, 0, 0, 0);
#pragma unroll
            for (int r = 0; r < 4; ++r) {
                const float sc = X[r];
                if (sc > bestS[pg][r]) { bestS[pg][r] = sc; bestC[pg][r] = codef; }
            }
        }
    };

    auto loadB = [&](const char* base, const char* ebase, Btile& T) {
        T.b0  = *(const s16x8*)(base);
        T.b1  = *(const s16x8*)(base + 1024);
        T.b2  = *(const s16x8*)(base + 2048);
        T.ne2 = *(const float*)(ebase);
    };

    // prologue: this team's tiles t0, t0+1 into the two register buffers
    Btile U, V;
    loadB(gp,        gpe,        U);
    loadB(gp + 3136, gpe + 3136, V);

    float cb = (float)(t0 * 16 + col);   // running code index (exact in fp32)
    for (int t = 0; t < HT; t += 2) {
        // trailing refills overread <=2 tiles past the team range; bytes are
        // valid codebook data or workspace (bins/esum) -- reads only.
        compute(U, cb);
        loadB(gp + 2 * 3136, gpe + 2 * 3136, U);
        compute(V, cb + 16.0f);
        loadB(gp + 3 * 3136, gpe + 3 * 3136, V);
        gp += 6272; gpe += 6272;
        cb += 32.0f;
        // convoy barrier every 8 tiles keeps each team's waves L1-coherent
        if ((t & 7) == 6) __syncthreads();
    }

    // ---- per-wave argmax across the 16 code-lanes; first-max tie-break ----
#pragma unroll
    for (int pg = 0; pg < 2; ++pg)
#pragma unroll
        for (int r = 0; r < 4; ++r) {
            float s = bestS[pg][r], c = bestC[pg][r];
#pragma unroll
            for (int off = 8; off >= 1; off >>= 1) {
                const float os = __shfl_xor(s, off);
                const float oc = __shfl_xor(c, off);
                if (os > s || (os == s && oc < c)) { s = os; c = oc; }
            }
            if (col == 0) {
                const int p = half * 32 + pg * 16 + (lane >> 4) * 4 + r;  // C/D row map
                teamS[team][p] = s;
                teamC[team][p] = c;
            }
        }
    __syncthreads();

    // ---- cross-team combine (codes ascend with team: later wins on strict >) --
    if (tid < PB) {
        float s = teamS[0][tid];
        float c = teamC[0][tid];
#pragma unroll
        for (int t = 1; t < 8; ++t) {
            const float st = teamS[t][tid];
            const float ct = teamC[t][tid];
            if (st > s) { s = st; c = ct; }
        }
        out_ind[n0 + tid] = c;
        best_c[tid] = (int)c;
        atomicAdd(&bins[(int)c], 1.0f);
    }
    __syncthreads();

    // ---- quantize gather (exact en = 0.5*(b0+b1+b2)) + embed_sum scatter ----
    if (tid < 4 * PB) {
        const int p = tid >> 2, q = tid & 3;
        const int b = best_c[p];
#pragma unroll
        for (int i = 0; i < 8; ++i)
            atomicAdd(&esum[(size_t)b * D + q * 8 + i], fn_r[i]);
        const char* bp = (const char*)bfrag + (size_t)(b >> 4) * 3136;
        const int lid = q * 16 + (b & 15);
        const s16x8 s0 = *(const s16x8*)(bp +    0 + lid * 16);
        const s16x8 s1 = *(const s16x8*)(bp + 1024 + lid * 16);
        const s16x8 s2 = *(const s16x8*)(bp + 2048 + lid * 16);
        float o[8];
#pragma unroll
        for (int i = 0; i < 8; ++i)
            o[i] = 0.5f * ((bf2f(s0[i]) + bf2f(s1[i])) + bf2f(s2[i]));   // exact
        float4 q0 = {o[0], o[1], o[2], o[3]};
        float4 q1 = {o[4], o[5], o[6], o[7]};
        *(float4*)&out_quant[(size_t)(n0 + p) * D + q * 8]     = q0;
        *(float4*)&out_quant[(size_t)(n0 + p) * D + q * 8 + 4] = q1;
    }
}

// ---------------- K3a: cluster_size_new + n_total reduce ----------------
__global__ void reduce_kernel(const float* __restrict__ cluster_size,
                              const float* __restrict__ bins,
                              float* __restrict__ out_cs,
                              float* __restrict__ n_total, int K) {
    __shared__ float red[256];
    float s = 0.f;
    for (int k = threadIdx.x; k < K; k += 256) {
        const float v = cluster_size[k] * DECAY + bins[k] * OMD;
        out_cs[k] = v;
        s += v;
    }
    red[threadIdx.x] = s;
    __syncthreads();
    for (int off = 128; off > 0; off >>= 1) {
        if (threadIdx.x < off) red[threadIdx.x] += red[threadIdx.x + off];
        __syncthreads();
    }
    if (threadIdx.x == 0) n_total[0] = red[0];
}

// ---------------- K3b: embed_avg_new + embed_updated ----------------
__global__ void finalize_kernel(const float* __restrict__ embed_avg,
                                const float* __restrict__ esum,
                                const float* __restrict__ out_cs,
                                const float* __restrict__ n_total,
                                float* __restrict__ out_avg,
                                float* __restrict__ out_upd,
                                int K) {
    const int i = blockIdx.x * blockDim.x + threadIdx.x;
    if (i >= K * D) return;
    const int k = i >> 5;   // D = 32
    const float avg = embed_avg[i] * DECAY + esum[i] * OMD;
    out_avg[i] = avg;
    const float nt = n_total[0];
    const float cs = out_cs[k];
    const float sm = (cs + EPS) / (nt + (float)K * EPS) * nt;
    out_upd[i] = avg / sm;
}

extern "C" void kernel_launch(void* const* d_in, const int* in_sizes, int n_in,
                              void* d_out, int out_size, void* d_ws, size_t ws_size,
                              hipStream_t stream) {
    const float* x            = (const float*)d_in[0];
    const float* embed        = (const float*)d_in[1];
    const float* cluster_size = (const float*)d_in[2];
    const float* embed_avg    = (const float*)d_in[3];

    const int KD = in_sizes[1];       // K*D = 131072
    const int K  = in_sizes[2];       // 4096
    const int N  = in_sizes[0] / D;   // 65536

    float* ws = (float*)d_ws;
    unsigned short* bfrag = (unsigned short*)ws;     // (K/16) tiles x 3136 B = K*49 floats
    float* bins  = ws + (size_t)K * 49;              // K
    float* esum  = bins + K;                         // KD
    float* ntot  = esum + KD;                        // 1   (total ~1.33 MB)

    float* out     = (float*)d_out;
    float* o_quant = out;                        // N*D
    float* o_ind   = o_quant + (size_t)N * D;    // N
    float* o_cs    = o_ind   + N;                // K
    float* o_avg   = o_cs    + K;                // KD
    float* o_upd   = o_avg   + KD;               // KD

    // zero the accumulators (bins, esum, ntot are contiguous)
    (void)hipMemsetAsync(bins, 0, (size_t)(K + KD + 1) * sizeof(float), stream);

    prep_codebook<<<(K + 63) / 64, 64, 0, stream>>>(embed, bfrag, K);
    assign_kernel<<<N / 64, 1024, 0, stream>>>(x, bfrag,
                                               o_quant, o_ind, bins, esum, N, K);
    reduce_kernel<<<1, 256, 0, stream>>>(cluster_size, bins, o_cs, ntot, K);
    finalize_kernel<<<(KD + 255) / 256, 256, 0, stream>>>(embed_avg, esum, o_cs, ntot,
                                                          o_avg, o_upd, K);
}

// Round 21
// 133.706 us; speedup vs baseline: 1.2257x; 1.2257x over previous
//
#include <hip/hip_runtime.h>
#include <float.h>

#define DECAY 0.1f
#define OMD   0.9f
#define EPS   1e-5f
#define NORM_EPS 1e-8f

static constexpr int D = 32;

typedef __attribute__((ext_vector_type(8))) short s16x8;
typedef __attribute__((ext_vector_type(4))) float f32x4_t;

__device__ __forceinline__ float bf2f(short s) {
    return __uint_as_float(((unsigned int)(unsigned short)s) << 16);
}

struct Split3 { short b0, b1, b2; };

// Exact 3-way bf16 truncation split: v == b0 + b1 + b2 (fp32 mantissa = 24 bits = 3x8).
__device__ __forceinline__ Split3 split3(float v) {
    const unsigned int u0 = __float_as_uint(v) & 0xFFFF0000u;
    const float r  = v - __uint_as_float(u0);
    const unsigned int u1 = __float_as_uint(r) & 0xFFFF0000u;
    const float r2 = r - __uint_as_float(u1);
    Split3 s;
    s.b0 = (short)(u0 >> 16);
    s.b1 = (short)(u1 >> 16);
    s.b2 = (short)(__float_as_uint(r2) >> 16);
    return s;
}

// ---------------- K1: normalize codebook + pack MFMA B-tiles ----------------
// Per 16-code tile (3136 B global): 3 planes x 1024 B of bf16 B-fragments, then
// 16 floats of -|en|^2 (64 B). Lane l's fragment of plane p is the contiguous
// 16 B at tile_base + p*1024 + l*16 -> direct global_load_dwordx4 to VGPRs.
// B[k][col] = 2*en[tile*16+col][k]; lane l holds k-chunk l>>4, col l&15.
__global__ void prep_codebook(const float* __restrict__ embed,
                              unsigned short* __restrict__ bfrag,
                              int K) {
    const int k = blockIdx.x * blockDim.x + threadIdx.x;
    if (k >= K) return;
    float v[D]; float ssq = 0.f;
#pragma unroll
    for (int d = 0; d < D; ++d) { v[d] = embed[(size_t)k * D + d]; ssq += v[d] * v[d]; }
    const float inv = 1.0f / (sqrtf(ssq) + NORM_EPS);
    float e2 = 0.f;
    short p0[D], p1[D], p2[D];
#pragma unroll
    for (int d = 0; d < D; ++d) {
        const float e = v[d] * inv;
        e2 += e * e;
        const Split3 s = split3(2.0f * e);   // fold the *2 into the splits (exact)
        p0[d] = s.b0; p1[d] = s.b1; p2[d] = s.b2;
    }
    char* base = (char*)bfrag + (size_t)(k >> 4) * 3136;   // tile base, bytes
    const int col = k & 15;
    *(float*)(base + 3072 + col * 4) = -e2;
#pragma unroll
    for (int g = 0; g < 4; ++g) {                 // k-chunk g -> lane g*16+col
        const int lid = g * 16 + col;
        s16x8 s0, s1, s2;
#pragma unroll
        for (int i = 0; i < 8; ++i) { s0[i] = p0[g*8+i]; s1[i] = p1[g*8+i]; s2[i] = p2[g*8+i]; }
        *(s16x8*)(base +    0 + lid * 16) = s0;
        *(s16x8*)(base + 1024 + lid * 16) = s1;
        *(s16x8*)(base + 2048 + lid * 16) = s2;
    }
}

// B tile held entirely in registers (13 VGPRs).
struct Btile { s16x8 b0, b1, b2; float ne2; };

// ---------------- K2: MFMA assignment, register-direct B, split-K x8 --------
// 512 thr = 8 waves, 32 points/block, grid = N/32 = 2048. 8 teams x 1 wave;
// team t scans tiles [t*32,(t+1)*32) for all 32 points. 6 split-products per
// tile (dropped a1*b2/a2*b1, ~2^-26 rel = fp32-rounding class). This is the
// measured-best structure (R15: 133.9 us); R16-R20 alternatives (separate
// scatter, global last-block combine, convoys, wide blocks) all regressed.
__global__ __launch_bounds__(512)
void assign_kernel(const float* __restrict__ x,
                   const unsigned short* __restrict__ bfrag,
                   float* __restrict__ out_quant,
                   float* __restrict__ out_ind,
                   float* __restrict__ bins,
                   float* __restrict__ esum,
                   int N, int K) {
    constexpr int PB = 32;
    __shared__ char  sm[6144];           // 2 point-groups x 3072 B A-fragments
    __shared__ float teamS[8][PB];
    __shared__ float teamC[8][PB];
    __shared__ int   best_c[PB];

    const int tid  = threadIdx.x;
    const int lane = tid & 63;
    const int team = tid >> 6;           // wave 0..7 = team 0..7
    const int n0   = blockIdx.x * PB;
    const int col  = lane & 15;

    float fn_r[8];
    // ---- phase 1: load + normalize + exact split into A-fragment LDS ----
    // 4 threads per point, 8 floats each; threads 128..511 idle here.
    if (tid < 4 * PB) {
        const int p = tid >> 2, q = tid & 3;
        const float* xp = &x[(size_t)(n0 + p) * D + q * 8];
        const float4 va = *(const float4*)(xp);
        const float4 vb = *(const float4*)(xp + 4);
        float ssq = va.x*va.x + va.y*va.y + va.z*va.z + va.w*va.w
                  + vb.x*vb.x + vb.y*vb.y + vb.z*vb.z + vb.w*vb.w;
        ssq += __shfl_xor(ssq, 1);
        ssq += __shfl_xor(ssq, 2);
        const float inv = 1.0f / (sqrtf(ssq) + NORM_EPS);
        fn_r[0]=va.x*inv; fn_r[1]=va.y*inv; fn_r[2]=va.z*inv; fn_r[3]=va.w*inv;
        fn_r[4]=vb.x*inv; fn_r[5]=vb.y*inv; fn_r[6]=vb.z*inv; fn_r[7]=vb.w*inv;
        // A-frag: group g=p>>4, k-chunk q -> lane q*16+(p&15), planes stride 1024B
        char* dst = &sm[(p >> 4) * 3072 + (q * 16 + (p & 15)) * 16];
        s16x8 s0, s1, s2;
#pragma unroll
        for (int i = 0; i < 8; ++i) {
            const Split3 s = split3(fn_r[i]);
            s0[i] = s.b0; s1[i] = s.b1; s2[i] = s.b2;
        }
        *(s16x8*)(dst) = s0; *(s16x8*)(dst + 1024) = s1; *(s16x8*)(dst + 2048) = s2;
    }
    __syncthreads();

    // ---- A fragments to registers: 2 point-groups x 3 planes (all waves) ----
    s16x8 A[2][3];
#pragma unroll
    for (int pg = 0; pg < 2; ++pg) {
#pragma unroll
        for (int pl = 0; pl < 3; ++pl)
            A[pg][pl] = *(const s16x8*)&sm[pg * 3072 + pl * 1024 + lane * 16];
    }

    float bestS[2][4], bestC[2][4];
#pragma unroll
    for (int pg = 0; pg < 2; ++pg)
#pragma unroll
        for (int r = 0; r < 4; ++r) { bestS[pg][r] = -1e30f; bestC[pg][r] = 0.f; }

    const int NT = K >> 4;               // 256 tiles
    const int HT = NT >> 3;              // 32 tiles per team
    const int t0 = team * HT;            // this team's first tile
    const char* gp  = (const char*)bfrag + (size_t)t0 * 3136 + lane * 16;
    const char* gpe = (const char*)bfrag + (size_t)t0 * 3136 + 3072 + (size_t)col * 4;

    auto compute = [&](const Btile& T, float codef) {
        const f32x4_t initX = {T.ne2, T.ne2, T.ne2, T.ne2};   // -|en|^2 folded into C
#pragma unroll
        for (int pg = 0; pg < 2; ++pg) {
            // 6 split products in ONE accumulator chain (C-in carries sum).
            f32x4_t X = __builtin_amdgcn_mfma_f32_16x16x32_bf16(A[pg][0], T.b0, initX, 0, 0, 0);
            X = __builtin_amdgcn_mfma_f32_16x16x32_bf16(A[pg][0], T.b1, X, 0, 0, 0);
            X = __builtin_amdgcn_mfma_f32_16x16x32_bf16(A[pg][1], T.b1, X, 0, 0, 0);
            X = __builtin_amdgcn_mfma_f32_16x16x32_bf16(A[pg][1], T.b0, X, 0, 0, 0);
            X = __builtin_amdgcn_mfma_f32_16x16x32_bf16(A[pg][0], T.b2, X, 0, 0, 0);
            X = __builtin_amdgcn_mfma_f32_16x16x32_bf16(A[pg][2], T.b0, X, 0, 0, 0);
#pragma unroll
            for (int r = 0; r < 4; ++r) {
                const float sc = X[r];
                if (sc > bestS[pg][r]) { bestS[pg][r] = sc; bestC[pg][r] = codef; }
            }
        }
    };

    auto loadB = [&](const char* base, const char* ebase, Btile& T) {
        T.b0  = *(const s16x8*)(base);
        T.b1  = *(const s16x8*)(base + 1024);
        T.b2  = *(const s16x8*)(base + 2048);
        T.ne2 = *(const float*)(ebase);
    };

    // prologue: this team's tiles t0, t0+1 into the two register buffers
    Btile U, V;
    loadB(gp,        gpe,        U);
    loadB(gp + 3136, gpe + 3136, V);

    float cb = (float)(t0 * 16 + col);   // running code index (exact in fp32)
    for (int t = 0; t < HT; t += 2) {
        // trailing refills overread <=2 tiles past the team range; bytes are
        // valid codebook data or workspace (bins/esum) -- reads only.
        compute(U, cb);
        loadB(gp + 2 * 3136, gpe + 2 * 3136, U);
        compute(V, cb + 16.0f);
        loadB(gp + 3 * 3136, gpe + 3 * 3136, V);
        gp += 6272; gpe += 6272;
        cb += 32.0f;
    }

    // ---- per-team argmax across the 16 code-lanes; first-max tie-break ----
#pragma unroll
    for (int pg = 0; pg < 2; ++pg)
#pragma unroll
        for (int r = 0; r < 4; ++r) {
            float s = bestS[pg][r], c = bestC[pg][r];
#pragma unroll
            for (int off = 8; off >= 1; off >>= 1) {
                const float os = __shfl_xor(s, off);
                const float oc = __shfl_xor(c, off);
                if (os > s || (os == s && oc < c)) { s = os; c = oc; }
            }
            if (col == 0) {
                const int p = pg * 16 + (lane >> 4) * 4 + r;   // C/D row map
                teamS[team][p] = s;
                teamC[team][p] = c;
            }
        }
    __syncthreads();

    // ---- cross-team combine (codes ascend with team: later wins on strict >) --
    if (tid < PB) {
        float s = teamS[0][tid];
        float c = teamC[0][tid];
#pragma unroll
        for (int t = 1; t < 8; ++t) {
            const float st = teamS[t][tid];
            const float ct = teamC[t][tid];
            if (st > s) { s = st; c = ct; }
        }
        out_ind[n0 + tid] = c;
        best_c[tid] = (int)c;
        atomicAdd(&bins[(int)c], 1.0f);
    }
    __syncthreads();

    // ---- quantize gather (exact en = 0.5*(b0+b1+b2)) + embed_sum scatter ----
    if (tid < 4 * PB) {
        const int p = tid >> 2, q = tid & 3;
        const int b = best_c[p];
#pragma unroll
        for (int i = 0; i < 8; ++i)
            atomicAdd(&esum[(size_t)b * D + q * 8 + i], fn_r[i]);
        const char* bp = (const char*)bfrag + (size_t)(b >> 4) * 3136;
        const int lid = q * 16 + (b & 15);
        const s16x8 s0 = *(const s16x8*)(bp +    0 + lid * 16);
        const s16x8 s1 = *(const s16x8*)(bp + 1024 + lid * 16);
        const s16x8 s2 = *(const s16x8*)(bp + 2048 + lid * 16);
        float o[8];
#pragma unroll
        for (int i = 0; i < 8; ++i)
            o[i] = 0.5f * ((bf2f(s0[i]) + bf2f(s1[i])) + bf2f(s2[i]));   // exact
        float4 q0 = {o[0], o[1], o[2], o[3]};
        float4 q1 = {o[4], o[5], o[6], o[7]};
        *(float4*)&out_quant[(size_t)(n0 + p) * D + q * 8]     = q0;
        *(float4*)&out_quant[(size_t)(n0 + p) * D + q * 8 + 4] = q1;
    }
}

// ---------------- K3a: cluster_size_new + n_total reduce ----------------
__global__ void reduce_kernel(const float* __restrict__ cluster_size,
                              const float* __restrict__ bins,
                              float* __restrict__ out_cs,
                              float* __restrict__ n_total, int K) {
    __shared__ float red[256];
    float s = 0.f;
    for (int k = threadIdx.x; k < K; k += 256) {
        const float v = cluster_size[k] * DECAY + bins[k] * OMD;
        out_cs[k] = v;
        s += v;
    }
    red[threadIdx.x] = s;
    __syncthreads();
    for (int off = 128; off > 0; off >>= 1) {
        if (threadIdx.x < off) red[threadIdx.x] += red[threadIdx.x + off];
        __syncthreads();
    }
    if (threadIdx.x == 0) n_total[0] = red[0];
}

// ---------------- K3b: embed_avg_new + embed_updated ----------------
__global__ void finalize_kernel(const float* __restrict__ embed_avg,
                                const float* __restrict__ esum,
                                const float* __restrict__ out_cs,
                                const float* __restrict__ n_total,
                                float* __restrict__ out_avg,
                                float* __restrict__ out_upd,
                                int K) {
    const int i = blockIdx.x * blockDim.x + threadIdx.x;
    if (i >= K * D) return;
    const int k = i >> 5;   // D = 32
    const float avg = embed_avg[i] * DECAY + esum[i] * OMD;
    out_avg[i] = avg;
    const float nt = n_total[0];
    const float cs = out_cs[k];
    const float sm = (cs + EPS) / (nt + (float)K * EPS) * nt;
    out_upd[i] = avg / sm;
}

extern "C" void kernel_launch(void* const* d_in, const int* in_sizes, int n_in,
                              void* d_out, int out_size, void* d_ws, size_t ws_size,
                              hipStream_t stream) {
    const float* x            = (const float*)d_in[0];
    const float* embed        = (const float*)d_in[1];
    const float* cluster_size = (const float*)d_in[2];
    const float* embed_avg    = (const float*)d_in[3];

    const int KD = in_sizes[1];       // K*D = 131072
    const int K  = in_sizes[2];       // 4096
    const int N  = in_sizes[0] / D;   // 65536

    float* ws = (float*)d_ws;
    unsigned short* bfrag = (unsigned short*)ws;     // (K/16) tiles x 3136 B = K*49 floats
    float* bins  = ws + (size_t)K * 49;              // K
    float* esum  = bins + K;                         // KD
    float* ntot  = esum + KD;                        // 1   (total ~1.33 MB)

    float* out     = (float*)d_out;
    float* o_quant = out;                        // N*D
    float* o_ind   = o_quant + (size_t)N * D;    // N
    float* o_cs    = o_ind   + N;                // K
    float* o_avg   = o_cs    + K;                // KD
    float* o_upd   = o_avg   + KD;               // KD

    // zero the accumulators (bins, esum, ntot are contiguous)
    (void)hipMemsetAsync(bins, 0, (size_t)(K + KD + 1) * sizeof(float), stream);

    prep_codebook<<<(K + 63) / 64, 64, 0, stream>>>(embed, bfrag, K);
    assign_kernel<<<N / 32, 512, 0, stream>>>(x, bfrag,
                                              o_quant, o_ind, bins, esum, N, K);
    reduce_kernel<<<1, 256, 0, stream>>>(cluster_size, bins, o_cs, ntot, K);
    finalize_kernel<<<(KD + 255) / 256, 256, 0, stream>>>(embed_avg, esum, o_cs, ntot,
                                                          o_avg, o_upd, K);
}